// Round 5
// baseline (675.177 us; speedup 1.0000x reference)
//
#include <hip/hip_runtime.h>
#include <math.h>

#define TS 256
#define BB 1024
#define NQ 8
#define INDIM 128
#define CATDIM 136

__device__ __forceinline__ float dpp_xor1(float v) {
    return __int_as_float(__builtin_amdgcn_mov_dpp(__float_as_int(v), 0xB1, 0xF, 0xF, true));
}
__device__ __forceinline__ float dpp_xor2(float v) {
    return __int_as_float(__builtin_amdgcn_mov_dpp(__float_as_int(v), 0x4E, 0xF, 0xF, true));
}
__device__ __forceinline__ float rdlane(float v, int l) {
    return __int_as_float(__builtin_amdgcn_readlane(__float_as_int(v), l));
}
__device__ __forceinline__ float rdfirst(float v) {
    return __int_as_float(__builtin_amdgcn_readfirstlane(__float_as_int(v)));
}
// opaque def: forbids rematerialization, forces VGPR residency
__device__ __forceinline__ void pinv(float& x) { asm volatile("" : "+v"(x)); }
// barrier draining LDS only (not the in-flight x prefetch)
__device__ __forceinline__ void lds_barrier() {
    asm volatile("s_waitcnt lgkmcnt(0)\n\ts_barrier" ::: "memory");
}
#define CMUL(zr, zi, ar, ai, br, bi) { float _t = (ar)*(br) - (ai)*(bi); zi = (ar)*(bi) + (ai)*(br); zr = _t; }

// One block = one batch element, all T=256 steps in-kernel.
// Wave w = gate (f,i,g,o). Lane holds amps k = j*64+lane, j=0..3.
// Algebraic folds (verified R3/R4): RX+RY0 -> product state; CNOT chain #1 ->
// gray-code selectors; CNOT chain #2 -> measurement sign prefixes.
// R5: asm-pinned loop invariants; single barrier/step via double-buffered gact
// + per-wave redundant LSTM + readlane h-broadcast.
__launch_bounds__(256, 4)
__global__ void qlstm_fused(const float* __restrict__ x,
    const float* __restrict__ Wf, const float* __restrict__ bf, const float* __restrict__ Pf,
    const float* __restrict__ Wi, const float* __restrict__ bi, const float* __restrict__ Pi,
    const float* __restrict__ Wg, const float* __restrict__ bg, const float* __restrict__ Pg,
    const float* __restrict__ Wo, const float* __restrict__ bo, const float* __restrict__ Po,
    float* __restrict__ out, float* __restrict__ hst, float* __restrict__ cst)
{
    const int b = blockIdx.x;
    const int tid = threadIdx.x;
    const int w = tid >> 6;
    const int lane = tid & 63;
    const int q = lane >> 3;
    const int kg = lane & 7;
    const int l7 = lane & 7;

    __shared__ float gact[2][4][8];

    const float* W; const float* bias; const float* P;
    if (w == 0)      { W = Wf; bias = bf; P = Pf; }
    else if (w == 1) { W = Wi; bias = bi; P = Pi; }
    else if (w == 2) { W = Wg; bias = bg; P = Pg; }
    else             { W = Wo; bias = bo; P = Po; }

    // ---- variational trig: layer0 feeds hoisted selects, layer1 -> SGPR ----
    float cp0[8], sp0[8], cp1[8], sp1[8];
    #pragma unroll
    for (int qq = 0; qq < 8; ++qq) {
        float h0 = 0.5f * P[qq];
        cp0[qq] = cosf(h0); sp0[qq] = sinf(h0);
        float h1 = 0.5f * P[8 + qq];
        cp1[qq] = rdfirst(cosf(h1)); sp1[qq] = rdfirst(sinf(h1));
    }

    // ---- weights for this lane's qubit (pinned) ----
    const float* Wq = W + q * CATDIM;
    float wx[16];
    #pragma unroll
    for (int c4 = 0; c4 < 4; ++c4) {
        float4 v = *(const float4*)(Wq + kg * 16 + c4 * 4);
        wx[c4*4+0] = v.x; wx[c4*4+1] = v.y; wx[c4*4+2] = v.z; wx[c4*4+3] = v.w;
    }
    #pragma unroll
    for (int i = 0; i < 16; ++i) pinv(wx[i]);
    float wh[8];
    #pragma unroll
    for (int j = 0; j < 8; ++j) { wh[j] = Wq[INDIM + j]; pinv(wh[j]); }
    float bq = bias[q];
    pinv(bq);

    // ---- lane bits ----
    const int l0 = lane & 1, l1 = (lane >> 1) & 1, l2b = (lane >> 2) & 1;
    const int l3 = (lane >> 3) & 1, l4 = (lane >> 4) & 1, l5 = (lane >> 5) & 1;
    const int s0 = l0 ^ l1, s1 = l1 ^ l2b, s2 = l2b ^ l3, s3 = l3 ^ l4, s4 = l4 ^ l5;

    // ---- hoisted build-factor values (pinned) ----
    float u7 = s0 ? sp0[7] : cp0[7], w7 = s0 ? -cp0[7] : sp0[7];
    float u6 = s1 ? sp0[6] : cp0[6], w6 = s1 ? -cp0[6] : sp0[6];
    float u5 = s2 ? sp0[5] : cp0[5], w5 = s2 ? -cp0[5] : sp0[5];
    float u4 = s3 ? sp0[4] : cp0[4], w4_ = s3 ? -cp0[4] : sp0[4];
    float u3 = s4 ? sp0[3] : cp0[3], w3_ = s4 ? -cp0[3] : sp0[3];
    float uga = l5 ? sp0[2] : cp0[2], wga = l5 ? -cp0[2] : sp0[2];
    float ugb = l5 ? cp0[2] : sp0[2], wgb = l5 ? sp0[2] : -cp0[2];
    pinv(u7); pinv(w7); pinv(u6); pinv(w6); pinv(u5); pinv(w5);
    pinv(u4); pinv(w4_); pinv(u3); pinv(w3_);
    pinv(uga); pinv(wga); pinv(ugb); pinv(wgb);
    const float c00 = cp0[0], s00 = sp0[0], c01 = cp0[1], s01 = sp0[1];

    // ---- hoisted RY1 per-lane signed sines (pinned) ----
    float sv2 = l5 ? sp1[2] : -sp1[2];
    float sv3 = l4 ? sp1[3] : -sp1[3];
    float sv4 = l3 ? sp1[4] : -sp1[4];
    float sv5 = l2b ? sp1[5] : -sp1[5];
    float sv6 = l1 ? sp1[6] : -sp1[6];
    float sv7 = l0 ? sp1[7] : -sp1[7];
    pinv(sv2); pinv(sv3); pinv(sv4); pinv(sv5); pinv(sv6); pinv(sv7);

    // ---- hoisted measurement sign prefixes (pinned) ----
    int pr_ = l5;            float sg2 = pr_ ? -1.f : 1.f;
    pr_ ^= l4;               float sg3 = pr_ ? -1.f : 1.f;
    pr_ ^= l3;               float sg4 = pr_ ? -1.f : 1.f;
    pr_ ^= l2b;              float sg5 = pr_ ? -1.f : 1.f;
    pr_ ^= l1;               float sg6 = pr_ ? -1.f : 1.f;
    pr_ ^= l0;               float sg7 = pr_ ? -1.f : 1.f;
    pinv(sg2); pinv(sg3); pinv(sg4); pinv(sg5); pinv(sg6); pinv(sg7);

    // write slot for this wave's activation
    const int qr = ((lane & 1) << 2) | (lane & 2) | ((lane >> 2) & 1);
    const int wslot = w * 8 + qr;

    // per-wave replicated LSTM state: every lane holds c[lane&7]
    float c_reg = 0.f;
    float hv = 0.f;
    float hs0 = 0.f, hs1 = 0.f, hs2 = 0.f, hs3 = 0.f;
    float hs4 = 0.f, hs5 = 0.f, hs6 = 0.f, hs7 = 0.f;

    // ---- x row for t=0 + running prefetch pointer ----
    float4 xv[4];
    {
        const float* xr = x + (size_t)b * INDIM + kg * 16;
        #pragma unroll
        for (int c4 = 0; c4 < 4; ++c4) xv[c4] = *(const float4*)(xr + c4 * 4);
    }
    const float* xp = x + ((size_t)BB + b) * INDIM + kg * 16;

    for (int t = 0; t < TS; ++t) {
        const int p = t & 1;

        // ---- x-part of angle ----
        float partial =
            xv[0].x*wx[0]  + xv[0].y*wx[1]  + xv[0].z*wx[2]  + xv[0].w*wx[3] +
            xv[1].x*wx[4]  + xv[1].y*wx[5]  + xv[1].z*wx[6]  + xv[1].w*wx[7] +
            xv[2].x*wx[8]  + xv[2].y*wx[9]  + xv[2].z*wx[10] + xv[2].w*wx[11] +
            xv[3].x*wx[12] + xv[3].y*wx[13] + xv[3].z*wx[14] + xv[3].w*wx[15];

        float4 xn[4];
        #pragma unroll
        for (int c4 = 0; c4 < 4; ++c4) xn[c4] = *(const float4*)(xp + c4 * 4);
        xp += (t < TS - 2) ? (size_t)(BB * INDIM) : 0;

        partial += dpp_xor1(partial);
        partial += dpp_xor2(partial);
        partial += __shfl_xor(partial, 4, 64);

        float ang = partial + bq
            + wh[0]*hs0 + wh[1]*hs1 + wh[2]*hs2 + wh[3]*hs3
            + wh[4]*hs4 + wh[5]*hs5 + wh[6]*hs6 + wh[7]*hs7;

        // ---- one sincos per lane, broadcast via readlane -> SGPR ----
        float c_own, s_own;
        __sincosf(0.5f * ang, &s_own, &c_own);
        float cqs[8], sqs[8];
        #pragma unroll
        for (int qq = 0; qq < 8; ++qq) {
            cqs[qq] = rdlane(c_own, qq * 8);
            sqs[qq] = rdlane(s_own, qq * 8);
        }

        // ---- product state (RX*RY0), gray-code fold in pinned selectors ----
        float Mr = u7 * cqs[7], Mi = w7 * sqs[7];
        { float fr = u6 * cqs[6], fi = w6 * sqs[6]; CMUL(Mr, Mi, Mr, Mi, fr, fi); }
        { float fr = u5 * cqs[5], fi = w5 * sqs[5]; CMUL(Mr, Mi, Mr, Mi, fr, fi); }
        { float fr = u4 * cqs[4], fi = w4_ * sqs[4]; CMUL(Mr, Mi, Mr, Mi, fr, fi); }
        { float fr = u3 * cqs[3], fi = w3_ * sqs[3]; CMUL(Mr, Mi, Mr, Mi, fr, fi); }
        float gar = uga * cqs[2], gai = wga * sqs[2];
        float gbr = ugb * cqs[2], gbi = wgb * sqs[2];
        float MGar, MGai, MGbr, MGbi;
        CMUL(MGar, MGai, Mr, Mi, gar, gai);
        CMUL(MGbr, MGbi, Mr, Mi, gbr, gbi);
        float a1r = c01 * cqs[1], a1i = s01 * sqs[1];
        float b1r = s01 * cqs[1], b1i = -c01 * sqs[1];
        float a0r = c00 * cqs[0], a0i = s00 * sqs[0];
        float b0r = s00 * cqs[0], b0i = -c00 * sqs[0];
        float h00r, h00i, h10r, h10i, h11r, h11i, h01r, h01i;
        CMUL(h00r, h00i, a1r, a1i, a0r, a0i);
        CMUL(h10r, h10i, b1r, b1i, a0r, a0i);
        CMUL(h11r, h11i, b1r, b1i, b0r, b0i);
        CMUL(h01r, h01i, a1r, a1i, b0r, b0i);
        float re[4], im[4];
        CMUL(re[0], im[0], MGar, MGai, h00r, h00i);
        CMUL(re[1], im[1], MGbr, MGbi, h10r, h10i);
        CMUL(re[2], im[2], MGar, MGai, h11r, h11i);
        CMUL(re[3], im[3], MGbr, MGbi, h01r, h01i);

        // ---- RY layer 1 ----
        {   // wire0 (bit7): pairs (0,2),(1,3)
            float cp = cp1[0], sp = sp1[0], tr;
            tr=re[0]; re[0]=cp*tr-sp*re[2]; re[2]=sp*tr+cp*re[2];
            tr=re[1]; re[1]=cp*tr-sp*re[3]; re[3]=sp*tr+cp*re[3];
            tr=im[0]; im[0]=cp*tr-sp*im[2]; im[2]=sp*tr+cp*im[2];
            tr=im[1]; im[1]=cp*tr-sp*im[3]; im[3]=sp*tr+cp*im[3];
        }
        {   // wire1 (bit6): pairs (0,1),(2,3)
            float cp = cp1[1], sp = sp1[1], tr;
            tr=re[0]; re[0]=cp*tr-sp*re[1]; re[1]=sp*tr+cp*re[1];
            tr=re[2]; re[2]=cp*tr-sp*re[3]; re[3]=sp*tr+cp*re[3];
            tr=im[0]; im[0]=cp*tr-sp*im[1]; im[1]=sp*tr+cp*im[1];
            tr=im[2]; im[2]=cp*tr-sp*im[3]; im[3]=sp*tr+cp*im[3];
        }
        #define RY_X(MASKOP, cp, sv)                                  \
            _Pragma("unroll")                                         \
            for (int j = 0; j < 4; ++j) {                             \
                float pr = MASKOP(re[j]);                             \
                float pi = MASKOP(im[j]);                             \
                re[j] = (cp)*re[j] + (sv)*pr;                         \
                im[j] = (cp)*im[j] + (sv)*pi;                         \
            }
        #define SH32(v) __shfl_xor(v, 32, 64)
        #define SH16(v) __shfl_xor(v, 16, 64)
        #define SH8(v)  __shfl_xor(v, 8, 64)
        #define SH4(v)  __shfl_xor(v, 4, 64)
        RY_X(SH32, cp1[2], sv2)      // wire2 (bit5)
        RY_X(SH16, cp1[3], sv3)      // wire3 (bit4)
        RY_X(SH8,  cp1[4], sv4)      // wire4 (bit3)
        RY_X(SH4,  cp1[5], sv5)      // wire5 (bit2)
        RY_X(dpp_xor2, cp1[6], sv6)  // wire6 (bit1)
        RY_X(dpp_xor1, cp1[7], sv7)  // wire7 (bit0)

        // ---- measurement, CNOT chain #2 folded into signs ----
        float p0 = re[0]*re[0] + im[0]*im[0];
        float p1 = re[1]*re[1] + im[1]*im[1];
        float p2 = re[2]*re[2] + im[2]*im[2];
        float p3 = re[3]*re[3] + im[3]*im[3];
        float v0 = (p0 + p1) - (p2 + p3);        // wire0
        float D  = (p0 - p1) - (p2 - p3);        // shared combo
        float v1 = D;
        float v2 = sg2 * D;
        float v3 = sg3 * D;
        float v4 = sg4 * D;
        float v5 = sg5 * D;
        float v6 = sg6 * D;
        float v7 = sg7 * D;

        // ---- 8-value 64-lane reduction; result periodic mod 8 lanes ----
        {
            int c0 = lane & 1;
            float s, r;
            s = c0 ? v0 : v4; r = dpp_xor1(s); v0 = (c0 ? v4 : v0) + r;
            s = c0 ? v1 : v5; r = dpp_xor1(s); v1 = (c0 ? v5 : v1) + r;
            s = c0 ? v2 : v6; r = dpp_xor1(s); v2 = (c0 ? v6 : v2) + r;
            s = c0 ? v3 : v7; r = dpp_xor1(s); v3 = (c0 ? v7 : v3) + r;
            int c1 = lane & 2;
            s = c1 ? v0 : v2; r = dpp_xor2(s); v0 = (c1 ? v2 : v0) + r;
            s = c1 ? v1 : v3; r = dpp_xor2(s); v1 = (c1 ? v3 : v1) + r;
            int c2 = lane & 4;
            s = c2 ? v0 : v1; r = __shfl_xor(s, 4, 64); v0 = (c2 ? v1 : v0) + r;
            v0 += __shfl_xor(v0, 8, 64);
            v0 += __shfl_xor(v0, 16, 64);
            v0 += __shfl_xor(v0, 32, 64);
        }
        // every lane holds S[q], q = 4*l0 + 2*l1 + l2  (= qr)

        // ---- gate nonlinearity (all lanes; value valid on all) ----
        float a;
        if (w == 2) { float e2 = __expf(2.f * v0); a = (e2 - 1.f) / (e2 + 1.f); }
        else        { a = 1.f / (1.f + __expf(-v0)); }
        if (lane < 8) ((float*)gact)[p * 32 + wslot] = a;

        lds_barrier();

        // ---- per-wave redundant LSTM update (all lanes, qubit lane&7) ----
        {
            float fv = gact[p][0][l7];
            float iv = gact[p][1][l7];
            float gv = gact[p][2][l7];
            float ov = gact[p][3][l7];
            c_reg = fv * c_reg + iv * gv;
            float e2 = __expf(2.f * c_reg);
            hv = ov * ((e2 - 1.f) / (e2 + 1.f));
        }
        if (w == 0 && lane < 8)
            out[((size_t)t * BB + b) * NQ + lane] = hv;

        hs0 = rdlane(hv, 0); hs1 = rdlane(hv, 1);
        hs2 = rdlane(hv, 2); hs3 = rdlane(hv, 3);
        hs4 = rdlane(hv, 4); hs5 = rdlane(hv, 5);
        hs6 = rdlane(hv, 6); hs7 = rdlane(hv, 7);

        xv[0] = xn[0]; xv[1] = xn[1]; xv[2] = xn[2]; xv[3] = xn[3];
    }

    if (w == 0 && lane < 8) {
        hst[b * NQ + lane] = hv;
        cst[b * NQ + lane] = c_reg;
    }
}

extern "C" void kernel_launch(void* const* d_in, const int* in_sizes, int n_in,
                              void* d_out, int out_size, void* d_ws, size_t ws_size,
                              hipStream_t stream) {
    const float* x  = (const float*)d_in[0];
    const float* Wf = (const float*)d_in[1];
    const float* bf = (const float*)d_in[2];
    const float* Pf = (const float*)d_in[3];
    const float* Wi = (const float*)d_in[4];
    const float* bi = (const float*)d_in[5];
    const float* Pi = (const float*)d_in[6];
    const float* Wg = (const float*)d_in[7];
    const float* bg = (const float*)d_in[8];
    const float* Pg = (const float*)d_in[9];
    const float* Wo = (const float*)d_in[10];
    const float* bo = (const float*)d_in[11];
    const float* Po = (const float*)d_in[12];

    float* out = (float*)d_out;
    float* hst = out + (size_t)TS * BB * NQ;
    float* cst = hst + (size_t)BB * NQ;

    qlstm_fused<<<BB, 256, 0, stream>>>(x, Wf, bf, Pf, Wi, bi, Pi,
                                        Wg, bg, Pg, Wo, bo, Po,
                                        out, hst, cst);
}

// Round 6
// 665.801 us; speedup vs baseline: 1.0141x; 1.0141x over previous
//
#include <hip/hip_runtime.h>
#include <math.h>

#define TS 256
#define BB 1024
#define NQ 8
#define INDIM 128
#define CATDIM 136

typedef float v2f __attribute__((ext_vector_type(2)));

__device__ __forceinline__ float dpp_xor1(float v) {
    return __int_as_float(__builtin_amdgcn_mov_dpp(__float_as_int(v), 0xB1, 0xF, 0xF, true));
}
__device__ __forceinline__ float dpp_xor2(float v) {
    return __int_as_float(__builtin_amdgcn_mov_dpp(__float_as_int(v), 0x4E, 0xF, 0xF, true));
}
__device__ __forceinline__ float rdlane(float v, int l) {
    return __int_as_float(__builtin_amdgcn_readlane(__float_as_int(v), l));
}
__device__ __forceinline__ float rdfirst(float v) {
    return __int_as_float(__builtin_amdgcn_readfirstlane(__float_as_int(v)));
}
__device__ __forceinline__ void lds_barrier() {
    asm volatile("s_waitcnt lgkmcnt(0)\n\ts_barrier" ::: "memory");
}
__device__ __forceinline__ v2f mk2(float x, float y) { v2f r; r.x = x; r.y = y; return r; }
__device__ __forceinline__ void pin2(v2f& x) { asm volatile("" : "+v"(x)); }
__device__ __forceinline__ void pin1(float& x) { asm volatile("" : "+v"(x)); }

// ---- packed dual-FP32 (VOP3P) helpers ----
__device__ __forceinline__ v2f pk_mul(v2f a, v2f b) {
    v2f d; asm("v_pk_mul_f32 %0, %1, %2" : "=v"(d) : "v"(a), "v"(b)); return d;
}
__device__ __forceinline__ v2f pk_fma(v2f a, v2f b, v2f c) {
    v2f d; asm("v_pk_fma_f32 %0, %1, %2, %3" : "=v"(d) : "v"(a), "v"(b), "v"(c)); return d;
}
// d = a*b - c (negate c in both halves)
__device__ __forceinline__ v2f pk_fma_negc(v2f a, v2f b, v2f c) {
    v2f d; asm("v_pk_fma_f32 %0, %1, %2, %3 neg_lo:[0,0,1] neg_hi:[0,0,1]"
               : "=v"(d) : "v"(a), "v"(b), "v"(c)); return d;
}
// t = (a.lo*b.lo, a.hi*b.lo)   [both halves read b.lo]
__device__ __forceinline__ v2f pk_mul_t(v2f a, v2f b) {
    v2f d; asm("v_pk_mul_f32 %0, %1, %2 op_sel_hi:[1,0]" : "=v"(d) : "v"(a), "v"(b)); return d;
}
// d.lo = -a.hi*b.hi + t.lo ; d.hi = a.lo*b.hi + t.hi
__device__ __forceinline__ v2f pk_fma_cmul(v2f a, v2f b, v2f t) {
    v2f d; asm("v_pk_fma_f32 %0, %1, %2, %3 op_sel:[1,1,0] op_sel_hi:[0,1,1] neg_lo:[0,1,0]"
               : "=v"(d) : "v"(a), "v"(b), "v"(t)); return d;
}
// complex multiply: (ar*br - ai*bi, ar*bi + ai*br), a=(ar,ai), b=(br,bi)
__device__ __forceinline__ v2f cmul(v2f a, v2f b) { return pk_fma_cmul(a, b, pk_mul_t(a, b)); }

// One block = one batch element, all T=256 steps in-kernel (R4 structure).
// Wave w = gate (f,i,g,o). Lane holds amps k = j*64+lane, j=0..3.
// Folds (verified R3/R4): RX+RY0 -> product state; CNOT#1 -> gray-code
// selectors; CNOT#2 -> measurement signs. State packed (re,im) per VGPR pair.
__launch_bounds__(256, 4)
__global__ void qlstm_fused(const float* __restrict__ x,
    const float* __restrict__ Wf, const float* __restrict__ bf, const float* __restrict__ Pf,
    const float* __restrict__ Wi, const float* __restrict__ bi, const float* __restrict__ Pi,
    const float* __restrict__ Wg, const float* __restrict__ bg, const float* __restrict__ Pg,
    const float* __restrict__ Wo, const float* __restrict__ bo, const float* __restrict__ Po,
    float* __restrict__ out, float* __restrict__ hst, float* __restrict__ cst)
{
    const int b = blockIdx.x;
    const int tid = threadIdx.x;
    const int w = tid >> 6;
    const int lane = tid & 63;
    const int q = lane >> 3;
    const int kg = lane & 7;

    __shared__ float gact[4][8];
    __shared__ __align__(16) float hsh[8];
    __shared__ float csh[8];

    const float* W; const float* bias; const float* P;
    if (w == 0)      { W = Wf; bias = bf; P = Pf; }
    else if (w == 1) { W = Wi; bias = bi; P = Pi; }
    else if (w == 2) { W = Wg; bias = bg; P = Pg; }
    else             { W = Wo; bias = bo; P = Po; }

    // ---- variational trig: layer0 VGPR (feeds selects), layer1 SGPR ----
    float cp0[8], sp0[8], cp1[8], sp1[8];
    #pragma unroll
    for (int qq = 0; qq < 8; ++qq) {
        float h0 = 0.5f * P[qq];
        cp0[qq] = cosf(h0); sp0[qq] = sinf(h0);
        float h1 = 0.5f * P[8 + qq];
        cp1[qq] = rdfirst(cosf(h1)); sp1[qq] = rdfirst(sinf(h1));
    }

    // ---- weights, packed ----
    const float* Wq = W + q * CATDIM;
    v2f wxp[8];
    #pragma unroll
    for (int c4 = 0; c4 < 4; ++c4) {
        float4 v = *(const float4*)(Wq + kg * 16 + c4 * 4);
        wxp[c4*2+0] = mk2(v.x, v.y);
        wxp[c4*2+1] = mk2(v.z, v.w);
    }
    #pragma unroll
    for (int i = 0; i < 8; ++i) pin2(wxp[i]);
    v2f whp[4];
    #pragma unroll
    for (int j = 0; j < 4; ++j) { whp[j] = mk2(Wq[INDIM + 2*j], Wq[INDIM + 2*j + 1]); pin2(whp[j]); }
    float bq = bias[q];
    pin1(bq);

    // ---- lane bits / gray-code selectors ----
    const int l0 = lane & 1, l1 = (lane >> 1) & 1, l2b = (lane >> 2) & 1;
    const int l3 = (lane >> 3) & 1, l4 = (lane >> 4) & 1, l5 = (lane >> 5) & 1;
    const int s0 = l0 ^ l1, s1 = l1 ^ l2b, s2 = l2b ^ l3, s3 = l3 ^ l4, s4 = l4 ^ l5;

    // ---- hoisted build-factor pairs: (u, w) per wire ----
    v2f uw7 = mk2(s0 ? sp0[7] : cp0[7], s0 ? -cp0[7] : sp0[7]);
    v2f uw6 = mk2(s1 ? sp0[6] : cp0[6], s1 ? -cp0[6] : sp0[6]);
    v2f uw5 = mk2(s2 ? sp0[5] : cp0[5], s2 ? -cp0[5] : sp0[5]);
    v2f uw4 = mk2(s3 ? sp0[4] : cp0[4], s3 ? -cp0[4] : sp0[4]);
    v2f uw3 = mk2(s4 ? sp0[3] : cp0[3], s4 ? -cp0[3] : sp0[3]);
    v2f uwga = mk2(l5 ? sp0[2] : cp0[2], l5 ? -cp0[2] : sp0[2]);
    v2f uwgb = mk2(l5 ? cp0[2] : sp0[2], l5 ? sp0[2] : -cp0[2]);
    pin2(uw7); pin2(uw6); pin2(uw5); pin2(uw4); pin2(uw3); pin2(uwga); pin2(uwgb);
    const float c00 = cp0[0], s00 = sp0[0], c01 = cp0[1], s01 = sp0[1];

    // ---- hoisted RY1 packed constants, wires 2..7 ----
    v2f cppk[6], svpk[6];
    {
        const int lb[6] = { l5, l4, l3, l2b, l1, l0 };
        #pragma unroll
        for (int k = 0; k < 6; ++k) {
            float cp = cp1[2 + k];
            float sv = lb[k] ? sp1[2 + k] : -sp1[2 + k];
            cppk[k] = mk2(cp, cp);
            svpk[k] = mk2(sv, sv);
            pin2(cppk[k]); pin2(svpk[k]);
        }
    }

    // ---- hoisted measurement sign prefixes ----
    int pr_ = l5;            float sg2 = pr_ ? -1.f : 1.f;
    pr_ ^= l4;               float sg3 = pr_ ? -1.f : 1.f;
    pr_ ^= l3;               float sg4 = pr_ ? -1.f : 1.f;
    pr_ ^= l2b;              float sg5 = pr_ ? -1.f : 1.f;
    pr_ ^= l1;               float sg6 = pr_ ? -1.f : 1.f;
    pr_ ^= l0;               float sg7 = pr_ ? -1.f : 1.f;
    pin1(sg2); pin1(sg3); pin1(sg4); pin1(sg5); pin1(sg6); pin1(sg7);

    if (tid < 8) { hsh[tid] = 0.f; csh[tid] = 0.f; }
    __syncthreads();

    // ---- x row t=0 + running prefetch pointer ----
    float4 xv[4];
    {
        const float* xr = x + (size_t)b * INDIM + kg * 16;
        #pragma unroll
        for (int c4 = 0; c4 < 4; ++c4) xv[c4] = *(const float4*)(xr + c4 * 4);
    }
    const float* xp = x + ((size_t)BB + b) * INDIM + kg * 16;

    for (int t = 0; t < TS; ++t) {
        // ---- x-dot, packed ----
        v2f acc = pk_mul(mk2(xv[0].x, xv[0].y), wxp[0]);
        acc = pk_fma(mk2(xv[0].z, xv[0].w), wxp[1], acc);
        acc = pk_fma(mk2(xv[1].x, xv[1].y), wxp[2], acc);
        acc = pk_fma(mk2(xv[1].z, xv[1].w), wxp[3], acc);
        acc = pk_fma(mk2(xv[2].x, xv[2].y), wxp[4], acc);
        acc = pk_fma(mk2(xv[2].z, xv[2].w), wxp[5], acc);
        acc = pk_fma(mk2(xv[3].x, xv[3].y), wxp[6], acc);
        acc = pk_fma(mk2(xv[3].z, xv[3].w), wxp[7], acc);
        float partial = acc.x + acc.y;

        // prefetch row t+1
        float4 xn[4];
        #pragma unroll
        for (int c4 = 0; c4 < 4; ++c4) xn[c4] = *(const float4*)(xp + c4 * 4);
        xp += (t < TS - 2) ? (size_t)(BB * INDIM) : 0;

        partial += dpp_xor1(partial);
        partial += dpp_xor2(partial);
        partial += __shfl_xor(partial, 4, 64);

        // ---- h-dot, packed ----
        float4 h01 = *(const float4*)&hsh[0];
        float4 h23 = *(const float4*)&hsh[4];
        v2f hacc = pk_mul(mk2(h01.x, h01.y), whp[0]);
        hacc = pk_fma(mk2(h01.z, h01.w), whp[1], hacc);
        hacc = pk_fma(mk2(h23.x, h23.y), whp[2], hacc);
        hacc = pk_fma(mk2(h23.z, h23.w), whp[3], hacc);
        float ang = partial + bq + hacc.x + hacc.y;

        // ---- one sincos per lane, broadcast via readlane ----
        float c_own, s_own;
        __sincosf(0.5f * ang, &s_own, &c_own);
        float cqs[8], sqs[8];
        #pragma unroll
        for (int qq = 0; qq < 8; ++qq) {
            cqs[qq] = rdlane(c_own, qq * 8);
            sqs[qq] = rdlane(s_own, qq * 8);
        }

        // ---- product state build (packed complex) ----
        v2f M = mk2(uw7.x * cqs[7], uw7.y * sqs[7]);
        M = cmul(M, mk2(uw6.x * cqs[6], uw6.y * sqs[6]));
        M = cmul(M, mk2(uw5.x * cqs[5], uw5.y * sqs[5]));
        M = cmul(M, mk2(uw4.x * cqs[4], uw4.y * sqs[4]));
        M = cmul(M, mk2(uw3.x * cqs[3], uw3.y * sqs[3]));
        v2f MGa = cmul(M, mk2(uwga.x * cqs[2], uwga.y * sqs[2]));
        v2f MGb = cmul(M, mk2(uwgb.x * cqs[2], uwgb.y * sqs[2]));
        v2f a1 = mk2(c01 * cqs[1], s01 * sqs[1]);
        v2f b1 = mk2(s01 * cqs[1], -(c01 * sqs[1]));
        v2f a0 = mk2(c00 * cqs[0], s00 * sqs[0]);
        v2f b0 = mk2(s00 * cqs[0], -(c00 * sqs[0]));
        v2f z0 = cmul(MGa, cmul(a1, a0));
        v2f z1 = cmul(MGb, cmul(b1, a0));
        v2f z2 = cmul(MGa, cmul(b1, b0));
        v2f z3 = cmul(MGb, cmul(a1, b0));

        // ---- RY layer 1: register wires scalar (SGPR trig) ----
        {   // wire0 (bit7): pairs (z0,z2),(z1,z3)
            float cp = cp1[0], sp = sp1[0], tr;
            tr=z0.x; z0.x=cp*tr-sp*z2.x; z2.x=sp*tr+cp*z2.x;
            tr=z0.y; z0.y=cp*tr-sp*z2.y; z2.y=sp*tr+cp*z2.y;
            tr=z1.x; z1.x=cp*tr-sp*z3.x; z3.x=sp*tr+cp*z3.x;
            tr=z1.y; z1.y=cp*tr-sp*z3.y; z3.y=sp*tr+cp*z3.y;
        }
        {   // wire1 (bit6): pairs (z0,z1),(z2,z3)
            float cp = cp1[1], sp = sp1[1], tr;
            tr=z0.x; z0.x=cp*tr-sp*z1.x; z1.x=sp*tr+cp*z1.x;
            tr=z0.y; z0.y=cp*tr-sp*z1.y; z1.y=sp*tr+cp*z1.y;
            tr=z2.x; z2.x=cp*tr-sp*z3.x; z3.x=sp*tr+cp*z3.x;
            tr=z2.y; z2.y=cp*tr-sp*z3.y; z3.y=sp*tr+cp*z3.y;
        }
        // ---- RY layer 1: shuffle wires, packed FMA ----
        #define RYP(SHUF, CPP, SVP) {                                   \
            v2f p_;                                                     \
            p_.x = SHUF(z0.x); p_.y = SHUF(z0.y);                       \
            z0 = pk_fma(z0, CPP, pk_mul(p_, SVP));                      \
            p_.x = SHUF(z1.x); p_.y = SHUF(z1.y);                       \
            z1 = pk_fma(z1, CPP, pk_mul(p_, SVP));                      \
            p_.x = SHUF(z2.x); p_.y = SHUF(z2.y);                       \
            z2 = pk_fma(z2, CPP, pk_mul(p_, SVP));                      \
            p_.x = SHUF(z3.x); p_.y = SHUF(z3.y);                       \
            z3 = pk_fma(z3, CPP, pk_mul(p_, SVP));                      \
        }
        #define SH32(v) __shfl_xor(v, 32, 64)
        #define SH16(v) __shfl_xor(v, 16, 64)
        #define SH8(v)  __shfl_xor(v, 8, 64)
        #define SH4(v)  __shfl_xor(v, 4, 64)
        RYP(SH32, cppk[0], svpk[0])      // wire2 (bit5)
        RYP(SH16, cppk[1], svpk[1])      // wire3 (bit4)
        RYP(SH8,  cppk[2], svpk[2])      // wire4 (bit3)
        RYP(SH4,  cppk[3], svpk[3])      // wire5 (bit2)
        RYP(dpp_xor2, cppk[4], svpk[4])  // wire6 (bit1)
        RYP(dpp_xor1, cppk[5], svpk[5])  // wire7 (bit0)

        // ---- measurement ----
        v2f q0 = pk_mul(z0, z0), q1 = pk_mul(z1, z1);
        v2f q2 = pk_mul(z2, z2), q3 = pk_mul(z3, z3);
        float p0 = q0.x + q0.y, p1 = q1.x + q1.y;
        float p2 = q2.x + q2.y, p3 = q3.x + q3.y;
        float v0 = (p0 + p1) - (p2 + p3);
        float D  = (p0 - p1) - (p2 - p3);
        float v1 = D;
        float v2 = sg2 * D;
        float v3 = sg3 * D;
        float v4 = sg4 * D;
        float v5 = sg5 * D;
        float v6 = sg6 * D;
        float v7 = sg7 * D;

        // ---- 8-value 64-lane reduction ----
        {
            int c0 = lane & 1;
            float s, r;
            s = c0 ? v0 : v4; r = dpp_xor1(s); v0 = (c0 ? v4 : v0) + r;
            s = c0 ? v1 : v5; r = dpp_xor1(s); v1 = (c0 ? v5 : v1) + r;
            s = c0 ? v2 : v6; r = dpp_xor1(s); v2 = (c0 ? v6 : v2) + r;
            s = c0 ? v3 : v7; r = dpp_xor1(s); v3 = (c0 ? v7 : v3) + r;
            int c1 = lane & 2;
            s = c1 ? v0 : v2; r = dpp_xor2(s); v0 = (c1 ? v2 : v0) + r;
            s = c1 ? v1 : v3; r = dpp_xor2(s); v1 = (c1 ? v3 : v1) + r;
            int c2 = lane & 4;
            s = c2 ? v0 : v1; r = __shfl_xor(s, 4, 64); v0 = (c2 ? v1 : v0) + r;
            v0 += __shfl_xor(v0, 8, 64);
            v0 += __shfl_xor(v0, 16, 64);
            v0 += __shfl_xor(v0, 32, 64);
        }
        // lane l holds S[q], q = 4*l0 + 2*l1 + l2

        if (lane < 8) {
            int qr = ((lane & 1) << 2) | (lane & 2) | ((lane >> 2) & 1);
            float a;
            if (w == 2) { float e2 = __expf(2.f * v0); a = (e2 - 1.f) / (e2 + 1.f); }
            else        { a = 1.f / (1.f + __expf(-v0)); }
            gact[w][qr] = a;
        }
        lds_barrier();

        if (tid < 8) {
            float fv = gact[0][tid], iv = gact[1][tid], gv = gact[2][tid], ov = gact[3][tid];
            float cv = csh[tid];
            cv = fv * cv + iv * gv;
            float e2 = __expf(2.f * cv);
            float hv = ov * ((e2 - 1.f) / (e2 + 1.f));
            csh[tid] = cv; hsh[tid] = hv;
            out[((size_t)t * BB + b) * NQ + tid] = hv;
        }
        lds_barrier();

        xv[0] = xn[0]; xv[1] = xn[1]; xv[2] = xn[2]; xv[3] = xn[3];
    }

    if (tid < 8) {
        hst[b * NQ + tid] = hsh[tid];
        cst[b * NQ + tid] = csh[tid];
    }
}

extern "C" void kernel_launch(void* const* d_in, const int* in_sizes, int n_in,
                              void* d_out, int out_size, void* d_ws, size_t ws_size,
                              hipStream_t stream) {
    const float* x  = (const float*)d_in[0];
    const float* Wf = (const float*)d_in[1];
    const float* bf = (const float*)d_in[2];
    const float* Pf = (const float*)d_in[3];
    const float* Wi = (const float*)d_in[4];
    const float* bi = (const float*)d_in[5];
    const float* Pi = (const float*)d_in[6];
    const float* Wg = (const float*)d_in[7];
    const float* bg = (const float*)d_in[8];
    const float* Pg = (const float*)d_in[9];
    const float* Wo = (const float*)d_in[10];
    const float* bo = (const float*)d_in[11];
    const float* Po = (const float*)d_in[12];

    float* out = (float*)d_out;
    float* hst = out + (size_t)TS * BB * NQ;
    float* cst = hst + (size_t)BB * NQ;

    qlstm_fused<<<BB, 256, 0, stream>>>(x, Wf, bf, Pf, Wi, bi, Pi,
                                        Wg, bg, Pg, Wo, bo, Po,
                                        out, hst, cst);
}

// Round 7
// 665.462 us; speedup vs baseline: 1.0146x; 1.0005x over previous
//
#include <hip/hip_runtime.h>
#include <math.h>

#define TS 256
#define BB 1024
#define NQ 8
#define INDIM 128
#define CATDIM 136

typedef float v2f __attribute__((ext_vector_type(2)));

__device__ __forceinline__ float dpp_xor1(float v) {
    return __int_as_float(__builtin_amdgcn_mov_dpp(__float_as_int(v), 0xB1, 0xF, 0xF, true));
}
__device__ __forceinline__ float dpp_xor2(float v) {
    return __int_as_float(__builtin_amdgcn_mov_dpp(__float_as_int(v), 0x4E, 0xF, 0xF, true));
}
__device__ __forceinline__ float dpp_xor8(float v) {   // row_ror:8 == xor 8 within 16-lane row
    return __int_as_float(__builtin_amdgcn_mov_dpp(__float_as_int(v), 0x128, 0xF, 0xF, true));
}
__device__ __forceinline__ float rdlane(float v, int l) {
    return __int_as_float(__builtin_amdgcn_readlane(__float_as_int(v), l));
}
__device__ __forceinline__ float rdfirst(float v) {
    return __int_as_float(__builtin_amdgcn_readfirstlane(__float_as_int(v)));
}
__device__ __forceinline__ void lds_barrier() {
    asm volatile("s_waitcnt lgkmcnt(0)\n\ts_barrier" ::: "memory");
}
__device__ __forceinline__ v2f mk2(float x, float y) { v2f r; r.x = x; r.y = y; return r; }
__device__ __forceinline__ void pin2(v2f& x) { asm volatile("" : "+v"(x)); }
__device__ __forceinline__ void pin1(float& x) { asm volatile("" : "+v"(x)); }

// ---- packed dual-FP32 (VOP3P) helpers ----
__device__ __forceinline__ v2f pk_mul(v2f a, v2f b) {
    v2f d; asm("v_pk_mul_f32 %0, %1, %2" : "=v"(d) : "v"(a), "v"(b)); return d;
}
__device__ __forceinline__ v2f pk_fma(v2f a, v2f b, v2f c) {
    v2f d; asm("v_pk_fma_f32 %0, %1, %2, %3" : "=v"(d) : "v"(a), "v"(b), "v"(c)); return d;
}
// t = (a.lo*b.lo, a.hi*b.lo)
__device__ __forceinline__ v2f pk_mul_t(v2f a, v2f b) {
    v2f d; asm("v_pk_mul_f32 %0, %1, %2 op_sel_hi:[1,0]" : "=v"(d) : "v"(a), "v"(b)); return d;
}
// d.lo = -a.hi*b.hi + t.lo ; d.hi = a.lo*b.hi + t.hi
__device__ __forceinline__ v2f pk_fma_cmul(v2f a, v2f b, v2f t) {
    v2f d; asm("v_pk_fma_f32 %0, %1, %2, %3 op_sel:[1,1,0] op_sel_hi:[0,1,1] neg_lo:[0,1,0]"
               : "=v"(d) : "v"(a), "v"(b), "v"(t)); return d;
}
__device__ __forceinline__ v2f cmul(v2f a, v2f b) { return pk_fma_cmul(a, b, pk_mul_t(a, b)); }

// ============ Kernel 1: xproj[b][t][w*8+q] = x[t][b]·W_w[q][:128] + bias ============
// Block = one batch element b; wave wv handles t = wv, wv+4, ...
__launch_bounds__(256)
__global__ void qlstm_xproj(const float* __restrict__ x,
    const float* __restrict__ Wf, const float* __restrict__ bf,
    const float* __restrict__ Wi, const float* __restrict__ bi,
    const float* __restrict__ Wg, const float* __restrict__ bg,
    const float* __restrict__ Wo, const float* __restrict__ bo,
    float* __restrict__ xproj)
{
    const int b = blockIdx.x;
    const int wv = threadIdx.x >> 6;
    const int lane = threadIdx.x & 63;
    const int q = lane >> 3;
    const int kg = lane & 7;

    const float* Ws[4] = { Wf, Wi, Wg, Wo };
    const float* bs[4] = { bf, bi, bg, bo };
    float4 wfrag[4][4];
    float bias_w[4];
    #pragma unroll
    for (int g = 0; g < 4; ++g) {
        const float* Wq = Ws[g] + q * CATDIM + kg * 16;
        #pragma unroll
        for (int c4 = 0; c4 < 4; ++c4) wfrag[g][c4] = *(const float4*)(Wq + c4 * 4);
        bias_w[g] = bs[g][q];
    }

    for (int t = wv; t < TS; t += 4) {
        const float* xr = x + ((size_t)t * BB + b) * INDIM + kg * 16;
        float4 x0 = *(const float4*)(xr);
        float4 x1 = *(const float4*)(xr + 4);
        float4 x2 = *(const float4*)(xr + 8);
        float4 x3 = *(const float4*)(xr + 12);
        float* outrow = xproj + ((size_t)b * TS + t) * 32;
        #pragma unroll
        for (int g = 0; g < 4; ++g) {
            float p =
                x0.x*wfrag[g][0].x + x0.y*wfrag[g][0].y + x0.z*wfrag[g][0].z + x0.w*wfrag[g][0].w +
                x1.x*wfrag[g][1].x + x1.y*wfrag[g][1].y + x1.z*wfrag[g][1].z + x1.w*wfrag[g][1].w +
                x2.x*wfrag[g][2].x + x2.y*wfrag[g][2].y + x2.z*wfrag[g][2].z + x2.w*wfrag[g][2].w +
                x3.x*wfrag[g][3].x + x3.y*wfrag[g][3].y + x3.z*wfrag[g][3].z + x3.w*wfrag[g][3].w;
            p += dpp_xor1(p);
            p += dpp_xor2(p);
            p += __shfl_xor(p, 4, 64);
            if (kg == 0) outrow[g * 8 + q] = p + bias_w[g];
        }
    }
}

// ============ Kernel 2: recurrent loop, angles from LDS-staged xproj ============
__launch_bounds__(256, 4)
__global__ void qlstm_fused(const float* __restrict__ xproj,
    const float* __restrict__ Wf, const float* __restrict__ Pf,
    const float* __restrict__ Wi, const float* __restrict__ Pi,
    const float* __restrict__ Wg, const float* __restrict__ Pg,
    const float* __restrict__ Wo, const float* __restrict__ Po,
    float* __restrict__ out, float* __restrict__ hst, float* __restrict__ cst)
{
    const int b = blockIdx.x;
    const int tid = threadIdx.x;
    const int w = tid >> 6;
    const int lane = tid & 63;
    const int q = lane >> 3;

    __shared__ float xplds[TS * 32];          // 32 KB: this block's angle bases
    __shared__ float gact[4][8];
    __shared__ __align__(16) float hsh[8];
    __shared__ float csh[8];

    const float* W; const float* P;
    if (w == 0)      { W = Wf; P = Pf; }
    else if (w == 1) { W = Wi; P = Pi; }
    else if (w == 2) { W = Wg; P = Pg; }
    else             { W = Wo; P = Po; }

    // ---- stage xproj for this b (coalesced float4) ----
    {
        const float4* src4 = (const float4*)(xproj + (size_t)b * (TS * 32));
        float4* dst4 = (float4*)xplds;
        #pragma unroll
        for (int i = 0; i < 8; ++i) dst4[tid + i * 256] = src4[tid + i * 256];
    }

    // ---- variational trig: layer0 VGPR (feeds selects), layer1 SGPR ----
    float cp0[8], sp0[8], cp1[8], sp1[8];
    #pragma unroll
    for (int qq = 0; qq < 8; ++qq) {
        float h0 = 0.5f * P[qq];
        cp0[qq] = cosf(h0); sp0[qq] = sinf(h0);
        float h1 = 0.5f * P[8 + qq];
        cp1[qq] = rdfirst(cosf(h1)); sp1[qq] = rdfirst(sinf(h1));
    }

    // ---- h-weights for this lane's qubit, packed ----
    const float* Wq = W + q * CATDIM;
    v2f whp[4];
    #pragma unroll
    for (int j = 0; j < 4; ++j) { whp[j] = mk2(Wq[INDIM + 2*j], Wq[INDIM + 2*j + 1]); pin2(whp[j]); }

    // ---- lane bits / gray-code selectors ----
    const int l0 = lane & 1, l1 = (lane >> 1) & 1, l2b = (lane >> 2) & 1;
    const int l3 = (lane >> 3) & 1, l4 = (lane >> 4) & 1, l5 = (lane >> 5) & 1;
    const int s0 = l0 ^ l1, s1 = l1 ^ l2b, s2 = l2b ^ l3, s3 = l3 ^ l4, s4 = l4 ^ l5;

    // ---- hoisted build-factor pairs (u, w) per wire ----
    v2f uw7 = mk2(s0 ? sp0[7] : cp0[7], s0 ? -cp0[7] : sp0[7]);
    v2f uw6 = mk2(s1 ? sp0[6] : cp0[6], s1 ? -cp0[6] : sp0[6]);
    v2f uw5 = mk2(s2 ? sp0[5] : cp0[5], s2 ? -cp0[5] : sp0[5]);
    v2f uw4 = mk2(s3 ? sp0[4] : cp0[4], s3 ? -cp0[4] : sp0[4]);
    v2f uw3 = mk2(s4 ? sp0[3] : cp0[3], s4 ? -cp0[3] : sp0[3]);
    v2f uwga = mk2(l5 ? sp0[2] : cp0[2], l5 ? -cp0[2] : sp0[2]);
    v2f uwgb = mk2(l5 ? cp0[2] : sp0[2], l5 ? sp0[2] : -cp0[2]);
    pin2(uw7); pin2(uw6); pin2(uw5); pin2(uw4); pin2(uw3); pin2(uwga); pin2(uwgb);
    const float c00 = cp0[0], s00 = sp0[0], c01 = cp0[1], s01 = sp0[1];

    // ---- hoisted RY1 packed constants, wires 2..7 ----
    v2f cppk[6], svpk[6];
    {
        const int lb[6] = { l5, l4, l3, l2b, l1, l0 };
        #pragma unroll
        for (int k = 0; k < 6; ++k) {
            float cp = cp1[2 + k];
            float sv = lb[k] ? sp1[2 + k] : -sp1[2 + k];
            cppk[k] = mk2(cp, cp);
            svpk[k] = mk2(sv, sv);
            pin2(cppk[k]); pin2(svpk[k]);
        }
    }

    // ---- hoisted measurement sign prefixes ----
    int pr_ = l5;            float sg2 = pr_ ? -1.f : 1.f;
    pr_ ^= l4;               float sg3 = pr_ ? -1.f : 1.f;
    pr_ ^= l3;               float sg4 = pr_ ? -1.f : 1.f;
    pr_ ^= l2b;              float sg5 = pr_ ? -1.f : 1.f;
    pr_ ^= l1;               float sg6 = pr_ ? -1.f : 1.f;
    pr_ ^= l0;               float sg7 = pr_ ? -1.f : 1.f;
    pin1(sg2); pin1(sg3); pin1(sg4); pin1(sg5); pin1(sg6); pin1(sg7);

    if (tid < 8) { hsh[tid] = 0.f; csh[tid] = 0.f; }
    __syncthreads();

    for (int t = 0; t < TS; ++t) {
        // ---- angle = staged xproj (+bias) + h-dot ----
        float xb = xplds[t * 32 + w * 8 + q];
        float4 h01 = *(const float4*)&hsh[0];
        float4 h23 = *(const float4*)&hsh[4];
        v2f hacc = pk_mul(mk2(h01.x, h01.y), whp[0]);
        hacc = pk_fma(mk2(h01.z, h01.w), whp[1], hacc);
        hacc = pk_fma(mk2(h23.x, h23.y), whp[2], hacc);
        hacc = pk_fma(mk2(h23.z, h23.w), whp[3], hacc);
        float ang = xb + hacc.x + hacc.y;

        // ---- one sincos per lane, broadcast via readlane ----
        float c_own, s_own;
        __sincosf(0.5f * ang, &s_own, &c_own);
        float cqs[8], sqs[8];
        #pragma unroll
        for (int qq = 0; qq < 8; ++qq) {
            cqs[qq] = rdlane(c_own, qq * 8);
            sqs[qq] = rdlane(s_own, qq * 8);
        }

        // ---- product state build (packed complex, tree-assoc) ----
        v2f f7 = mk2(uw7.x * cqs[7], uw7.y * sqs[7]);
        v2f f6 = mk2(uw6.x * cqs[6], uw6.y * sqs[6]);
        v2f f5 = mk2(uw5.x * cqs[5], uw5.y * sqs[5]);
        v2f f4 = mk2(uw4.x * cqs[4], uw4.y * sqs[4]);
        v2f f3 = mk2(uw3.x * cqs[3], uw3.y * sqs[3]);
        v2f t76 = cmul(f7, f6);
        v2f t54 = cmul(f5, f4);
        v2f t7654 = cmul(t76, t54);
        v2f M = cmul(t7654, f3);
        v2f MGa = cmul(M, mk2(uwga.x * cqs[2], uwga.y * sqs[2]));
        v2f MGb = cmul(M, mk2(uwgb.x * cqs[2], uwgb.y * sqs[2]));
        v2f a1 = mk2(c01 * cqs[1], s01 * sqs[1]);
        v2f b1 = mk2(s01 * cqs[1], -(c01 * sqs[1]));
        v2f a0 = mk2(c00 * cqs[0], s00 * sqs[0]);
        v2f b0 = mk2(s00 * cqs[0], -(c00 * sqs[0]));
        v2f h00 = cmul(a1, a0), h10 = cmul(b1, a0);
        v2f h11 = cmul(b1, b0), h01p = cmul(a1, b0);
        v2f z0 = cmul(MGa, h00);
        v2f z1 = cmul(MGb, h10);
        v2f z2 = cmul(MGa, h11);
        v2f z3 = cmul(MGb, h01p);

        // ---- RY layer 1: register wires scalar (SGPR trig) ----
        {   // wire0 (bit7): pairs (z0,z2),(z1,z3)
            float cp = cp1[0], sp = sp1[0], tr;
            tr=z0.x; z0.x=cp*tr-sp*z2.x; z2.x=sp*tr+cp*z2.x;
            tr=z0.y; z0.y=cp*tr-sp*z2.y; z2.y=sp*tr+cp*z2.y;
            tr=z1.x; z1.x=cp*tr-sp*z3.x; z3.x=sp*tr+cp*z3.x;
            tr=z1.y; z1.y=cp*tr-sp*z3.y; z3.y=sp*tr+cp*z3.y;
        }
        {   // wire1 (bit6): pairs (z0,z1),(z2,z3)
            float cp = cp1[1], sp = sp1[1], tr;
            tr=z0.x; z0.x=cp*tr-sp*z1.x; z1.x=sp*tr+cp*z1.x;
            tr=z0.y; z0.y=cp*tr-sp*z1.y; z1.y=sp*tr+cp*z1.y;
            tr=z2.x; z2.x=cp*tr-sp*z3.x; z3.x=sp*tr+cp*z3.x;
            tr=z2.y; z2.y=cp*tr-sp*z3.y; z3.y=sp*tr+cp*z3.y;
        }
        // ---- RY layer 1: shuffle wires, packed FMA ----
        #define RYP(SHUF, CPP, SVP) {                                   \
            v2f p_;                                                     \
            p_.x = SHUF(z0.x); p_.y = SHUF(z0.y);                       \
            z0 = pk_fma(z0, CPP, pk_mul(p_, SVP));                      \
            p_.x = SHUF(z1.x); p_.y = SHUF(z1.y);                       \
            z1 = pk_fma(z1, CPP, pk_mul(p_, SVP));                      \
            p_.x = SHUF(z2.x); p_.y = SHUF(z2.y);                       \
            z2 = pk_fma(z2, CPP, pk_mul(p_, SVP));                      \
            p_.x = SHUF(z3.x); p_.y = SHUF(z3.y);                       \
            z3 = pk_fma(z3, CPP, pk_mul(p_, SVP));                      \
        }
        #define SH32(v) __shfl_xor(v, 32, 64)
        #define SH16(v) __shfl_xor(v, 16, 64)
        #define SH4(v)  __shfl_xor(v, 4, 64)
        RYP(SH32, cppk[0], svpk[0])      // wire2 (bit5)  [DS]
        RYP(SH16, cppk[1], svpk[1])      // wire3 (bit4)  [DS]
        RYP(dpp_xor8, cppk[2], svpk[2])  // wire4 (bit3)  [DPP row_ror:8]
        RYP(SH4,  cppk[3], svpk[3])      // wire5 (bit2)  [DS]
        RYP(dpp_xor2, cppk[4], svpk[4])  // wire6 (bit1)  [DPP]
        RYP(dpp_xor1, cppk[5], svpk[5])  // wire7 (bit0)  [DPP]

        // ---- measurement ----
        v2f q0 = pk_mul(z0, z0), q1 = pk_mul(z1, z1);
        v2f q2 = pk_mul(z2, z2), q3 = pk_mul(z3, z3);
        float p0 = q0.x + q0.y, p1 = q1.x + q1.y;
        float p2 = q2.x + q2.y, p3 = q3.x + q3.y;
        float v0 = (p0 + p1) - (p2 + p3);
        float D  = (p0 - p1) - (p2 - p3);
        float v1 = D;
        float v2 = sg2 * D;
        float v3 = sg3 * D;
        float v4 = sg4 * D;
        float v5 = sg5 * D;
        float v6 = sg6 * D;
        float v7 = sg7 * D;

        // ---- 8-value 64-lane reduction ----
        {
            int c0 = lane & 1;
            float s, r;
            s = c0 ? v0 : v4; r = dpp_xor1(s); v0 = (c0 ? v4 : v0) + r;
            s = c0 ? v1 : v5; r = dpp_xor1(s); v1 = (c0 ? v5 : v1) + r;
            s = c0 ? v2 : v6; r = dpp_xor1(s); v2 = (c0 ? v6 : v2) + r;
            s = c0 ? v3 : v7; r = dpp_xor1(s); v3 = (c0 ? v7 : v3) + r;
            int c1 = lane & 2;
            s = c1 ? v0 : v2; r = dpp_xor2(s); v0 = (c1 ? v2 : v0) + r;
            s = c1 ? v1 : v3; r = dpp_xor2(s); v1 = (c1 ? v3 : v1) + r;
            int c2 = lane & 4;
            s = c2 ? v0 : v1; r = __shfl_xor(s, 4, 64); v0 = (c2 ? v1 : v0) + r;
            v0 += dpp_xor8(v0);
            v0 += __shfl_xor(v0, 16, 64);
            v0 += __shfl_xor(v0, 32, 64);
        }
        // lane l holds S[q], q = 4*l0 + 2*l1 + l2

        if (lane < 8) {
            int qr = ((lane & 1) << 2) | (lane & 2) | ((lane >> 2) & 1);
            float a;
            if (w == 2) { float e2 = __expf(2.f * v0); a = (e2 - 1.f) / (e2 + 1.f); }
            else        { a = 1.f / (1.f + __expf(-v0)); }
            gact[w][qr] = a;
        }
        lds_barrier();

        if (tid < 8) {
            float fv = gact[0][tid], iv = gact[1][tid], gv = gact[2][tid], ov = gact[3][tid];
            float cv = csh[tid];
            cv = fv * cv + iv * gv;
            float e2 = __expf(2.f * cv);
            float hv = ov * ((e2 - 1.f) / (e2 + 1.f));
            csh[tid] = cv; hsh[tid] = hv;
            out[((size_t)t * BB + b) * NQ + tid] = hv;
        }
        lds_barrier();
    }

    if (tid < 8) {
        hst[b * NQ + tid] = hsh[tid];
        cst[b * NQ + tid] = csh[tid];
    }
}

extern "C" void kernel_launch(void* const* d_in, const int* in_sizes, int n_in,
                              void* d_out, int out_size, void* d_ws, size_t ws_size,
                              hipStream_t stream) {
    const float* x  = (const float*)d_in[0];
    const float* Wf = (const float*)d_in[1];
    const float* bf = (const float*)d_in[2];
    const float* Pf = (const float*)d_in[3];
    const float* Wi = (const float*)d_in[4];
    const float* bi = (const float*)d_in[5];
    const float* Pi = (const float*)d_in[6];
    const float* Wg = (const float*)d_in[7];
    const float* bg = (const float*)d_in[8];
    const float* Pg = (const float*)d_in[9];
    const float* Wo = (const float*)d_in[10];
    const float* bo = (const float*)d_in[11];
    const float* Po = (const float*)d_in[12];

    float* out = (float*)d_out;
    float* hst = out + (size_t)TS * BB * NQ;
    float* cst = hst + (size_t)BB * NQ;
    float* xproj = (float*)d_ws;             // TS*BB*32 floats = 33.5 MB scratch

    qlstm_xproj<<<BB, 256, 0, stream>>>(x, Wf, bf, Wi, bi, Wg, bg, Wo, bo, xproj);
    qlstm_fused<<<BB, 256, 0, stream>>>(xproj, Wf, Pf, Wi, Pi, Wg, Pg, Wo, Po,
                                        out, hst, cst);
}